// Round 6
// baseline (86.904 us; speedup 1.0000x reference)
//
#include <hip/hip_runtime.h>
#include <stdint.h>

#define SLEN   4096
#define BATCH  4
#define DIM    64
#define HPROJ  16
#define KMAX   64
#define GRID   512       // blocks; LDS 49KB -> 3 blocks/CU -> 768 co-resident capacity > 512
#define KL_CAP 4096      // exact worst case (each key once)
#define PB_CAP 1024      // per-block pair cap (expected ~0; guarded writes, validated R2-R5)

__device__ inline float dot64(const float* a, const float* b)
{
    float s = 0.0f;
#pragma unroll
    for (int d = 0; d < DIM; ++d) s = fmaf(a[d], b[d], s);
    return s;
}

__global__ void __launch_bounds__(256, 4) k_fused(
    const float* __restrict__ qup, const float* __restrict__ kup,
    const float* __restrict__ W,
    unsigned char* __restrict__ qh, unsigned char* __restrict__ kh,
    unsigned long long* __restrict__ qsig, unsigned long long* __restrict__ ksig,
    unsigned long long* __restrict__ insmask,
    unsigned* __restrict__ barA, unsigned* __restrict__ barD,
    int* __restrict__ out)
{
    __shared__ __align__(16) float Ws[DIM * HPROJ];
    __shared__ unsigned long long ks[KL_CAP];
    __shared__ unsigned short kl[KL_CAP];
    __shared__ unsigned int pairs[PB_CAP];
    __shared__ int nk, np;

    const int tid = threadIdx.x;
    for (int i = tid; i < DIM * HPROJ; i += 256) Ws[i] = W[i];
    if (tid == 0) { nk = 0; np = 0; }
    __syncthreads();

    const int gid = blockIdx.x * 256 + tid;

    // ---- -1 output init: 2 int4/thread x 131072 threads = 1,048,576 ints exactly ----
    const int4 m1 = make_int4(-1, -1, -1, -1);
    ((int4*)out)[gid] = m1;
    ((int4*)out)[gid + GRID * 256] = m1;

    // ---- phase 1: every 4th wave handles 64 tokens, 1 token/lane ----
    // Per-h fma order over d is sequential 0..63 — bit-identical to validated R1-R5.
    const int wid = gid >> 6;                       // global wave id, 0..2047
    if ((wid & 3) == 0) {
        const int token  = ((wid >> 2) << 6) | (tid & 63);   // 0..32767
        const int tensor = token >> 14;                      // 0=query, 1=key
        const int rem    = token & (BATCH * SLEN - 1);
        const int b      = rem >> 12;
        const int s      = rem & (SLEN - 1);
        const float* x = (tensor ? kup : qup) + (size_t)rem * DIM;

        float4 xv[16];
#pragma unroll
        for (int dv = 0; dv < 16; ++dv) xv[dv] = ((const float4*)x)[dv];

        float p[16];
#pragma unroll
        for (int h = 0; h < 16; ++h) p[h] = 0.0f;

#pragma unroll
        for (int dv = 0; dv < 16; ++dv) {
            const float4 v = xv[dv];
#pragma unroll
            for (int j = 0; j < 4; ++j) {
                const float xd = (j == 0) ? v.x : (j == 1) ? v.y : (j == 2) ? v.z : v.w;
                const float4* wr = (const float4*)&Ws[(dv * 4 + j) * HPROJ];  // wave-uniform b128
                const float4 w0 = wr[0], w1 = wr[1], w2 = wr[2], w3 = wr[3];
                p[0]  = fmaf(xd, w0.x, p[0]);  p[1]  = fmaf(xd, w0.y, p[1]);
                p[2]  = fmaf(xd, w0.z, p[2]);  p[3]  = fmaf(xd, w0.w, p[3]);
                p[4]  = fmaf(xd, w1.x, p[4]);  p[5]  = fmaf(xd, w1.y, p[5]);
                p[6]  = fmaf(xd, w1.z, p[6]);  p[7]  = fmaf(xd, w1.w, p[7]);
                p[8]  = fmaf(xd, w2.x, p[8]);  p[9]  = fmaf(xd, w2.y, p[9]);
                p[10] = fmaf(xd, w2.z, p[10]); p[11] = fmaf(xd, w2.w, p[11]);
                p[12] = fmaf(xd, w3.x, p[12]); p[13] = fmaf(xd, w3.y, p[13]);
                p[14] = fmaf(xd, w3.z, p[14]); p[15] = fmaf(xd, w3.w, p[15]);
            }
        }

        int acc = 0;
#pragma unroll
        for (int h = 0; h < 16; ++h) acc += (int)floorf(p[h] * 0.25f);  // /4 exact
        const unsigned char hash = (unsigned char)(acc & 63);            // Python mod 64
        if (tensor == 0) qh[rem] = hash; else kh[rem] = hash;

        if (b == BATCH - 1) {                       // wave-uniform branch (64-aligned tokens)
            unsigned long long bits = 0ull;
#pragma unroll
            for (int dv = 0; dv < 16; ++dv) {
                const float4 v = xv[dv];
                const int d = dv * 4;
                bits |= (unsigned long long)(v.x > 0.0f) << d;
                bits |= (unsigned long long)(v.y > 0.0f) << (d + 1);
                bits |= (unsigned long long)(v.z > 0.0f) << (d + 2);
                bits |= (unsigned long long)(v.w > 0.0f) << (d + 3);
            }
            if (tensor == 0) qsig[s] = bits; else ksig[s] = bits;
        }

        if (tensor == 1 && b == 0) {                // wave-uniform; Wu-Manber prefix filter
            const float4 a0 = ((const float4*)(qup + (size_t)s * DIM))[0];
            const float4 a1 = ((const float4*)(qup + (size_t)s * DIM))[1];
            const bool ins = ((a0.x > 0.0f) == (xv[0].x > 0.0f)) &
                             ((a0.y > 0.0f) == (xv[0].y > 0.0f)) &
                             ((a0.z > 0.0f) == (xv[0].z > 0.0f)) &
                             ((a0.w > 0.0f) == (xv[0].w > 0.0f)) &
                             ((a1.x > 0.0f) == (xv[1].x > 0.0f)) &
                             ((a1.y > 0.0f) == (xv[1].y > 0.0f));
            const unsigned long long bal = __ballot((int)ins);
            if ((tid & 63) == 0) insmask[s >> 6] = bal;   // bit L of word = token base+L
        }
    }

    // ---- grid barrier: release writes, arrive, poll (poison-aware base) ----
    __threadfence();
    __syncthreads();
    if (tid == 0) {
        const unsigned v = __hip_atomic_fetch_add(barA, 1u, __ATOMIC_ACQ_REL, __HIP_MEMORY_SCOPE_AGENT);
        const unsigned base = (v >= 0x80000000u) ? 0xAAAAAAAAu : 0u;   // 0xAA ws poison
        const unsigned target = base + GRID;
        int guard = 0;
        while (__hip_atomic_load(barA, __ATOMIC_ACQUIRE, __HIP_MEMORY_SCOPE_AGENT) < target) {
            __builtin_amdgcn_s_sleep(2);
            if (++guard > (1 << 20)) break;    // escape hatch: fail visibly, never hang
        }
    }
    __syncthreads();

    // ---- compact inserted keys (bitmask -> list), fully parallel ----
    if (tid < 64) {
        unsigned long long mw = insmask[tid];
        const int cnt = __popcll(mw);
        int pos = cnt ? atomicAdd(&nk, cnt) : 0;   // nk <= 4096 = KL_CAP structurally
        const int kb = tid * 64;
        while (mw) {
            const int bit = __ffsll((long long)mw) - 1;
            mw &= mw - 1;
            kl[pos++] = (unsigned short)(kb + bit);
        }
    }
    __syncthreads();
    const int m = nk;

    // q-side state: this block owns 8 q's, 32 threads each
    const int q   = blockIdx.x * 8 + (tid >> 5);
    const int l32 = tid & 31;
    const unsigned long long sv = qsig[q];
    const unsigned char q0 = qh[q], q1 = qh[SLEN + q],
                        q2 = qh[2 * SLEN + q], q3 = qh[3 * SLEN + q];

    // gather key signatures in parallel rounds
    for (int i = tid; i < m; i += 256) ks[i] = ksig[kl[i]];
    __syncthreads();

    // probe: exact 64-bit sig match, then per-batch LSH check
    for (int i = l32; i < m; i += 32) {
        if (ks[i] == sv) {
            const int k = kl[i];
            const unsigned char kh0 = kh[k], kh1 = kh[SLEN + k],
                                kh2 = kh[2 * SLEN + k], kh3 = kh[3 * SLEN + k];
            const unsigned qk = ((unsigned)(q & 4095) << 12) | (unsigned)k;
            if (q0 == kh0) { int pp = atomicAdd(&np, 1); if (pp < PB_CAP) pairs[pp] = (0u << 24) | qk; }
            if (q1 == kh1) { int pp = atomicAdd(&np, 1); if (pp < PB_CAP) pairs[pp] = (1u << 24) | qk; }
            if (q2 == kh2) { int pp = atomicAdd(&np, 1); if (pp < PB_CAP) pairs[pp] = (2u << 24) | qk; }
            if (q3 == kh3) { int pp = atomicAdd(&np, 1); if (pp < PB_CAP) pairs[pp] = (3u << 24) | qk; }
        }
    }
    __syncthreads();
    const int n = np < PB_CAP ? np : PB_CAP;

    // exact top-k rank among this block's pairs (desc, stable by index) — validated R2-R5
    for (int idx = tid; idx < n; idx += 256) {
        const unsigned u = pairs[idx];
        const int b = u >> 24, qq = (u >> 12) & 4095, k = u & 4095;
        const float* qr = qup + ((size_t)(b * SLEN + qq)) * DIM;
        const float si = dot64(qr, kup + ((size_t)(b * SLEN + k)) * DIM);
        int rank = 0;
        for (int j = 0; j < n; ++j) {
            const unsigned vv = pairs[j];
            if ((vv >> 12) == (u >> 12)) {
                const int kj = vv & 4095;
                const float sj = dot64(qr, kup + ((size_t)(b * SLEN + kj)) * DIM);
                rank += (sj > si) || (sj == si && kj < k);
            }
        }
        if (rank < KMAX)
            out[((size_t)(b * SLEN + qq)) * KMAX + rank] = k;
    }

    // ---- depart: last block restores barrier state to 0 (deterministic across replays) ----
    __syncthreads();
    if (tid == 0) {
        const unsigned d = __hip_atomic_fetch_add(barD, 1u, __ATOMIC_ACQ_REL, __HIP_MEMORY_SCOPE_AGENT);
        const unsigned based = (d >= 0x80000000u) ? 0xAAAAAAAAu : 0u;
        if (d == based + GRID - 1) {
            __hip_atomic_store(barA, 0u, __ATOMIC_RELAXED, __HIP_MEMORY_SCOPE_AGENT);
            __hip_atomic_store(barD, 0u, __ATOMIC_RELAXED, __HIP_MEMORY_SCOPE_AGENT);
        }
    }
}

extern "C" void kernel_launch(void* const* d_in, const int* in_sizes, int n_in,
                              void* d_out, int out_size, void* d_ws, size_t ws_size,
                              hipStream_t stream)
{
    const float* qup = (const float*)d_in[0];
    const float* kup = (const float*)d_in[1];
    const float* W   = (const float*)d_in[2];
    int* out = (int*)d_out;

    char* w = (char*)d_ws;
    unsigned long long* qsig    = (unsigned long long*)(w);            // 32 KB
    unsigned long long* ksig    = (unsigned long long*)(w + 32768);    // 32 KB
    unsigned char*      qh      = (unsigned char*)(w + 65536);         // 16 KB
    unsigned char*      kh      = (unsigned char*)(w + 81920);         // 16 KB
    unsigned long long* insmask = (unsigned long long*)(w + 98304);    // 512 B
    unsigned*           barA    = (unsigned*)(w + 98816);              // 4 B
    unsigned*           barD    = (unsigned*)(w + 98820);              // 4 B

    k_fused<<<GRID, 256, 0, stream>>>(qup, kup, W, qh, kh, qsig, ksig,
                                      insmask, barA, barD, out);
}

// Round 7
// 16.267 us; speedup vs baseline: 5.3423x; 5.3423x over previous
//
#include <hip/hip_runtime.h>
#include <stdint.h>

#define SLEN   4096
#define BATCH  4
#define DIM    64
#define HPROJ  16
#define KMAX   64

#define KL_CAP 4096      // exact worst case (every key inserted)
#define PB_CAP 1024      // per-block pair cap (expected ~0; guard validated R2-R5)
#define QB     32        // queries per k_query block
#define NQB    (SLEN / QB)

// ---------------- K_A: per-key signature + Wu-Manber inserted bit ----------------
__global__ void __launch_bounds__(256) k_keys(
    const float* __restrict__ qup, const float* __restrict__ kup,
    unsigned long long* __restrict__ ksig,
    unsigned long long* __restrict__ insmask)
{
    const int k = blockIdx.x * 256 + threadIdx.x;          // 0..4095

    // batch-3 key row sign bits (bit order validated R1-R5)
    const float* kr = kup + ((size_t)3 * SLEN + k) * DIM;
    unsigned long long bits = 0ull;
#pragma unroll
    for (int dv = 0; dv < 16; ++dv) {
        const float4 v = ((const float4*)kr)[dv];
        const int d = dv * 4;
        bits |= (unsigned long long)(v.x > 0.0f) << d;
        bits |= (unsigned long long)(v.y > 0.0f) << (d + 1);
        bits |= (unsigned long long)(v.z > 0.0f) << (d + 2);
        bits |= (unsigned long long)(v.w > 0.0f) << (d + 3);
    }
    ksig[k] = bits;

    // Wu-Manber: sign-prefix match q[0,k,:6] vs k[0,k,:6]
    const float* q0 = qup + (size_t)k * DIM;
    const float* k0 = kup + (size_t)k * DIM;
    const float4 qa = ((const float4*)q0)[0], qb = ((const float4*)q0)[1];
    const float4 ka = ((const float4*)k0)[0], kb = ((const float4*)k0)[1];
    const bool ins = ((qa.x > 0.0f) == (ka.x > 0.0f)) &
                     ((qa.y > 0.0f) == (ka.y > 0.0f)) &
                     ((qa.z > 0.0f) == (ka.z > 0.0f)) &
                     ((qa.w > 0.0f) == (ka.w > 0.0f)) &
                     ((qb.x > 0.0f) == (kb.x > 0.0f)) &
                     ((qb.y > 0.0f) == (kb.y > 0.0f));
    const unsigned long long bal = __ballot((int)ins);
    if ((threadIdx.x & 63) == 0) insmask[k >> 6] = bal;    // k is 64-aligned at lane 0
}

// ---------------- K_B: out-init + compact + probe + on-demand LSH + exact top-k ----------------
__device__ inline float dot64(const float* a, const float* b)
{
    float s = 0.0f;
#pragma unroll
    for (int d = 0; d < DIM; ++d) s = fmaf(a[d], b[d], s);
    return s;
}

// EXACT fma order of validated R1-R5 phase1: per h, accumulate d = 0..63 sequentially
__device__ inline int lsh_hash_row(const float* __restrict__ x, const float* Ws)
{
    int acc = 0;
    for (int h = 0; h < HPROJ; ++h) {
        float p = 0.0f;
#pragma unroll
        for (int d = 0; d < DIM; ++d) p = fmaf(x[d], Ws[d * HPROJ + h], p);
        acc += (int)floorf(p * 0.25f);     // /4 exact in fp32
    }
    return acc & 63;                        // Python mod 64
}

__global__ void __launch_bounds__(256) k_query(
    const float* __restrict__ qup, const float* __restrict__ kup,
    const float* __restrict__ W,
    const unsigned long long* __restrict__ ksig,
    const unsigned long long* __restrict__ insmask,
    int* __restrict__ out)
{
    __shared__ __align__(16) float Ws[DIM * HPROJ];
    __shared__ unsigned long long ks[KL_CAP];
    __shared__ unsigned short kl[KL_CAP];
    __shared__ unsigned int pairs[PB_CAP];
    __shared__ int nk, np;

    const int tid = threadIdx.x;
    for (int i = tid; i < DIM * HPROJ; i += 256) Ws[i] = W[i];
    if (tid == 0) { nk = 0; np = 0; }
    __syncthreads();

    // -1 init of this block's output slice (no cross-block aliasing: q-ranges partition out)
    const int qbase = blockIdx.x * QB;
#pragma unroll
    for (int b = 0; b < BATCH; ++b) {
        int4* dst = (int4*)(out + ((size_t)b * SLEN + qbase) * KMAX);
        for (int i = tid; i < QB * KMAX / 4; i += 256)
            dst[i] = make_int4(-1, -1, -1, -1);
    }

    // compact inserted keys (bitmask -> list), fully parallel
    if (tid < 64) {
        unsigned long long mw = insmask[tid];
        const int cnt = __popcll(mw);
        int pos = cnt ? atomicAdd(&nk, cnt) : 0;      // nk <= 4096 structurally
        const int kb = tid * 64;
        while (mw) {
            const int bit = __ffsll((long long)mw) - 1;
            mw &= mw - 1;
            kl[pos++] = (unsigned short)(kb + bit);
        }
    }
    __syncthreads();
    const int m = nk;

    // gather inserted keys' signatures (parallel rounds, L2-hot)
    for (int i = tid; i < m; i += 256) ks[i] = ksig[kl[i]];

    // own q signature (batch-3 q row; 8 threads per q compute redundantly — L1-hit)
    const int q = qbase + (tid & (QB - 1));
    const float* qr3 = qup + ((size_t)3 * SLEN + q) * DIM;
    unsigned long long sv = 0ull;
#pragma unroll
    for (int dv = 0; dv < 16; ++dv) {
        const float4 v = ((const float4*)qr3)[dv];
        const int d = dv * 4;
        sv |= (unsigned long long)(v.x > 0.0f) << d;
        sv |= (unsigned long long)(v.y > 0.0f) << (d + 1);
        sv |= (unsigned long long)(v.z > 0.0f) << (d + 2);
        sv |= (unsigned long long)(v.w > 0.0f) << (d + 3);
    }
    __syncthreads();

    // probe: 8 threads per q, key slice each; LSH hashes ONLY for sig-matched pairs
    const int slice = tid >> 5;                        // 0..7
    for (int i = slice; i < m; i += 8) {
        if (ks[i] == sv) {
            const int k = kl[i];
            for (int b = 0; b < BATCH; ++b) {
                const int hq = lsh_hash_row(qup + ((size_t)b * SLEN + q) * DIM, Ws);
                const int hk = lsh_hash_row(kup + ((size_t)b * SLEN + k) * DIM, Ws);
                if (hq == hk) {
                    const int pp = atomicAdd(&np, 1);
                    if (pp < PB_CAP)
                        pairs[pp] = ((unsigned)b << 24) | ((unsigned)(q & 4095) << 12) | (unsigned)k;
                }
            }
        }
    }
    __syncthreads();
    const int n = np < PB_CAP ? np : PB_CAP;

    // exact top-k rank among this block's pairs (desc, stable by index) — validated R2-R5
    for (int idx = tid; idx < n; idx += 256) {
        const unsigned u = pairs[idx];
        const int b = u >> 24, qq = (u >> 12) & 4095, k = u & 4095;
        const float* qr = qup + ((size_t)(b * SLEN + qq)) * DIM;
        const float si = dot64(qr, kup + ((size_t)(b * SLEN + k)) * DIM);
        int rank = 0;
        for (int j = 0; j < n; ++j) {
            const unsigned vv = pairs[j];
            if ((vv >> 12) == (u >> 12)) {             // same (b, q)
                const int kj = vv & 4095;
                const float sj = dot64(qr, kup + ((size_t)(b * SLEN + kj)) * DIM);
                rank += (sj > si) || (sj == si && kj < k);
            }
        }
        if (rank < KMAX)
            out[((size_t)(b * SLEN + qq)) * KMAX + rank] = k;
    }
}

extern "C" void kernel_launch(void* const* d_in, const int* in_sizes, int n_in,
                              void* d_out, int out_size, void* d_ws, size_t ws_size,
                              hipStream_t stream)
{
    const float* qup = (const float*)d_in[0];
    const float* kup = (const float*)d_in[1];
    const float* W   = (const float*)d_in[2];
    int* out = (int*)d_out;

    char* w = (char*)d_ws;
    unsigned long long* ksig    = (unsigned long long*)(w);          // 32 KB
    unsigned long long* insmask = (unsigned long long*)(w + 32768);  // 512 B

    k_keys<<<SLEN / 256, 256, 0, stream>>>(qup, kup, ksig, insmask);
    k_query<<<NQB, 256, 0, stream>>>(qup, kup, W, ksig, insmask, out);
}